// Round 7
// baseline (2015.023 us; speedup 1.0000x reference)
//
#include <hip/hip_runtime.h>
#include <math.h>

typedef _Float16 half_t;
typedef _Float16 f16x2 __attribute__((ext_vector_type(2)));
typedef _Float16 f16x4 __attribute__((ext_vector_type(4)));
typedef _Float16 f16x8 __attribute__((ext_vector_type(8)));
typedef float f32x4 __attribute__((ext_vector_type(4)));

#define D_PROT 512
#define D_TEXT 2048

// ---------------- utility: fp32 -> fp16 convert (vector x4) ----------------
__global__ void k_cvt4(const float* __restrict__ s, half_t* __restrict__ d, int n4) {
    int i = blockIdx.x * 256 + threadIdx.x;
    if (i < n4) {
        float4 v = ((const float4*)s)[i];
        f16x4 o;
        o.x = (_Float16)v.x; o.y = (_Float16)v.y;
        o.z = (_Float16)v.z; o.w = (_Float16)v.w;
        ((f16x4*)d)[i] = o;
    }
}

// ---------------- degree histogram ----------------
__global__ void k_deg(const int* __restrict__ dst, int E, int* __restrict__ deg) {
    int i = blockIdx.x * 256 + threadIdx.x;
    if (i < E) atomicAdd(&deg[dst[i]], 1);
}

__global__ void k_dinv(const int* __restrict__ deg, float* __restrict__ dinv, int n) {
    int i = blockIdx.x * 256 + threadIdx.x;
    if (i < n) dinv[i] = rsqrtf((float)deg[i] + 1.0f);
}

// ---------------- prefix sum (3-kernel) ----------------
__global__ void k_blocksum(const int* __restrict__ deg, int* __restrict__ bsum, int n) {
    __shared__ int sd[256];
    int i = blockIdx.x * 256 + threadIdx.x;
    sd[threadIdx.x] = (i < n) ? deg[i] : 0;
    __syncthreads();
    for (int s = 128; s > 0; s >>= 1) {
        if (threadIdx.x < s) sd[threadIdx.x] += sd[threadIdx.x + s];
        __syncthreads();
    }
    if (threadIdx.x == 0) bsum[blockIdx.x] = sd[0];
}

__global__ void k_scan_bsum(const int* __restrict__ bsum, int* __restrict__ boff, int nb) {
    if (threadIdx.x == 0 && blockIdx.x == 0) {
        int acc = 0;
        for (int i = 0; i < nb; i++) { boff[i] = acc; acc += bsum[i]; }
    }
}

__global__ void k_scan_final(const int* __restrict__ deg, const int* __restrict__ boff,
                             int* __restrict__ rowptr, int n) {
    __shared__ int sd[256];
    int i = blockIdx.x * 256 + threadIdx.x;
    int v = (i < n) ? deg[i] : 0;
    sd[threadIdx.x] = v;
    __syncthreads();
    for (int s = 1; s < 256; s <<= 1) {
        int t2 = (threadIdx.x >= s) ? sd[threadIdx.x - s] : 0;
        __syncthreads();
        sd[threadIdx.x] += t2;
        __syncthreads();
    }
    if (i < n) rowptr[i + 1] = boff[blockIdx.x] + sd[threadIdx.x];
}

// ---------------- CSR fill (atomic append) ----------------
__global__ void k_fill(const int* __restrict__ src, const int* __restrict__ dst, int E,
                       const int* __restrict__ rowptr, int* __restrict__ fill,
                       int* __restrict__ colidx) {
    int i = blockIdx.x * 256 + threadIdx.x;
    if (i < E) {
        int d = dst[i];
        int pos = atomicAdd(&fill[d], 1);
        colidx[rowptr[d] + pos] = src[i];
    }
}

// ---------------- GraphNorm ----------------
__global__ void k_gnreduce(const float* __restrict__ x, float* __restrict__ sums,
                           float* __restrict__ sumsq, int Nn) {
    int t = threadIdx.x;
    int c = t * 2;
    float s0 = 0, s1 = 0, q0 = 0, q1 = 0;
    for (int r = blockIdx.x; r < Nn; r += gridDim.x) {
        float2 v = *(const float2*)(x + (size_t)r * D_PROT + c);
        s0 += v.x; s1 += v.y; q0 += v.x * v.x; q1 += v.y * v.y;
    }
    atomicAdd(&sums[c], s0);  atomicAdd(&sums[c + 1], s1);
    atomicAdd(&sumsq[c], q0); atomicAdd(&sumsq[c + 1], q1);
}

__global__ void k_gnfinal(const float* __restrict__ sums, const float* __restrict__ sumsq,
                          const float* __restrict__ w, const float* __restrict__ b,
                          const float* __restrict__ ms, float* __restrict__ ab, float invN) {
    int d = blockIdx.x * 256 + threadIdx.x;
    if (d < D_PROT) {
        float mean = sums[d] * invN;
        float m2 = sumsq[d] * invN;
        float mm = mean * ms[d];
        float var = m2 - 2.f * mm * mean + mm * mm;
        float rstd = rsqrtf(var + 1e-5f);
        float a = rstd * w[d];
        ab[d] = a;
        ab[D_PROT + d] = b[d] - mm * a;
    }
}

__global__ void k_gnnorm(const float* __restrict__ x, const float* __restrict__ ab,
                         half_t* __restrict__ h, int n4) {
    int i = blockIdx.x * 256 + threadIdx.x;
    if (i < n4) {
        size_t idx = (size_t)i * 4;
        float4 v = *(const float4*)(x + idx);
        int d = (int)(idx & (D_PROT - 1));
        const float* a = ab;
        const float* bb = ab + D_PROT;
        f16x4 o;
        o.x = (_Float16)(v.x * a[d]     + bb[d]);
        o.y = (_Float16)(v.y * a[d + 1] + bb[d + 1]);
        o.z = (_Float16)(v.z * a[d + 2] + bb[d + 2]);
        o.w = (_Float16)(v.w * a[d + 3] + bb[d + 3]);
        *(f16x4*)(h + idx) = o;
    }
}

// ---------------- SGConv aggregation (CSR gather, 4-way unrolled) ----------------
__global__ void k_agg(const half_t* __restrict__ h, half_t* __restrict__ out,
                      const int* __restrict__ rowptr, const int* __restrict__ colidx,
                      const float* __restrict__ dinv) {
    int node = blockIdx.x;
    int t = threadIdx.x;
    float di = dinv[node];
    int beg = rowptr[node], end = rowptr[node + 1];
    const f16x4* hp = (const f16x4*)h;
    f16x4 sv = hp[node * 128 + t];
    float dii = di * di;
    float a0 = (float)sv.x * dii, a1 = (float)sv.y * dii;
    float a2 = (float)sv.z * dii, a3 = (float)sv.w * dii;
    int e = beg;
    for (; e + 4 <= end; e += 4) {
        int s0 = colidx[e],     s1 = colidx[e + 1];
        int s2 = colidx[e + 2], s3 = colidx[e + 3];
        float w0 = dinv[s0] * di, w1 = dinv[s1] * di;
        float w2 = dinv[s2] * di, w3 = dinv[s3] * di;
        f16x4 v0 = hp[s0 * 128 + t], v1 = hp[s1 * 128 + t];
        f16x4 v2 = hp[s2 * 128 + t], v3 = hp[s3 * 128 + t];
        a0 += w0 * (float)v0.x + w1 * (float)v1.x + w2 * (float)v2.x + w3 * (float)v3.x;
        a1 += w0 * (float)v0.y + w1 * (float)v1.y + w2 * (float)v2.y + w3 * (float)v3.y;
        a2 += w0 * (float)v0.z + w1 * (float)v1.z + w2 * (float)v2.z + w3 * (float)v3.z;
        a3 += w0 * (float)v0.w + w1 * (float)v1.w + w2 * (float)v2.w + w3 * (float)v3.w;
    }
    for (; e < end; ++e) {
        int s = colidx[e];
        float wgt = dinv[s] * di;
        f16x4 v = hp[s * 128 + t];
        a0 += wgt * (float)v.x; a1 += wgt * (float)v.y;
        a2 += wgt * (float)v.z; a3 += wgt * (float)v.w;
    }
    f16x4 o;
    o.x = (_Float16)a0; o.y = (_Float16)a1; o.z = (_Float16)a2; o.w = (_Float16)a3;
    ((f16x4*)out)[node * 128 + t] = o;
}

// ---------------- 256^2 8-wave GEMM, 2 barriers/tile (de-lockstepped) ----------------
// C[M,N] = A[M,K] @ W[N,K]^T + bias, activation. N % 256 == 0, K % 128 == 0.
// LDS per dbuf (64KB): A rows 0..255 x 64 halves at [0,16384), B at [16384,32768).
// T2 swizzle (R3-verified conflicts=0): read byte ^= ((row&7)<<4); staging source
// pre-swizzled with the same involution; linear gload_lds write + swz read = id.
// Per tile t (buf cur=t&1), ONLY the 2 required barriers:
//   [boundary bar from prev tile: tile t landed, and ALL waves' reads of buf nxt
//    are drained (their final MFMAs forced lgkm drains before that barrier)]
//   GLD A(t+1)x4 -> nxt                       (safe by boundary barrier)
//   24 ds_reads (B all, A all) -> regs; MFMA mi0..3 (32)
//   LGKM0 + BAR                               (all waves' reads of cur drained)
//   GLD B(t+2)x4 -> cur B region              (safe by mid barrier)
//   MFMA mi4..7 (32)
//   WAITV4 + BAR                              (drains B(t+1),A(t+1); keeps B(t+2))
// Waves are free to drift between barriers -> sibling wave's ds_reads overlap
// this wave's MFMAs; MFMA pipe stays fed. Never vmcnt(0) in loop.
#define FENCE() asm volatile("" ::: "memory")
#define BAR()   do { FENCE(); __builtin_amdgcn_s_barrier(); FENCE(); } while (0)
#define WAITV4() asm volatile("s_waitcnt vmcnt(4)" ::: "memory")
#define WAITV0() asm volatile("s_waitcnt vmcnt(0)" ::: "memory")
#define LGKM0()  asm volatile("s_waitcnt lgkmcnt(0)" ::: "memory")
#define GLD(src, dst) __builtin_amdgcn_global_load_lds( \
    (const __attribute__((address_space(1))) void*)(src), \
    (__attribute__((address_space(3))) void*)(dst), 16, 0, 0)
#define LDF(base, row, kk) \
    (*(const f16x8*)((base) + ((((row) * 128 + (kk) * 64 + fqo)) ^ (((row) & 7) << 4))))
#define MM(mi, nj, A_, B_) \
    acc[mi][nj] = __builtin_amdgcn_mfma_f32_16x16x32_f16(A_, B_, acc[mi][nj], 0, 0, 0)

template <int ACT, typename OUT_T>
__global__ __launch_bounds__(512, 2) void k_gemm8(const half_t* __restrict__ A,
                                                  const half_t* __restrict__ W,
                                                  const float* __restrict__ bias,
                                                  OUT_T* __restrict__ C,
                                                  int M, int N, int K) {
    __shared__ half_t sm[2][32768];
    // XCD-chunked bijective remap (nwg % 8 == 0 in all our launches): lowers HBM
    // fetch to ~A-once (R3: 335MB vs natural 829MB) — matters at high throughput.
    const int gx = gridDim.x;
    const int nwg = gx * gridDim.y;
    int b = blockIdx.y * gx + blockIdx.x;
    int w8 = ((nwg & 7) == 0) ? (b & 7) * (nwg >> 3) + (b >> 3) : b;
    const int bn = (w8 % gx) * 256;
    const int bm = (w8 / gx) * 256;

    const int t = threadIdx.x;
    const int w = t >> 6, lane = t & 63;
    const int fr = lane & 15, fq = lane >> 4;
    const int fqo = fq * 16;
    const int wm = (w >> 2) * 128, wn = (w & 3) * 64;
    const int NT = K >> 6;

    // staging: load l covers half-range [l*4096 + w*512 + lane*8, +8) (linear LDS
    // write); source index pre-swizzled with the T2 involution.
    int q0 = w * 512 + lane * 8;
    int q1 = 4096 + q0;
    int s0 = q0 ^ (((q0 >> 6) & 7) << 3);
    int s1 = q1 ^ (((q1 >> 6) & 7) << 3);
    int r0 = s0 >> 6, c0 = s0 & 63;
    int r1 = s1 >> 6, c1 = s1 & 63;
    const half_t* gAlo0 = A + (size_t)min(bm + r0, M - 1) * K + c0;
    const half_t* gAlo1 = A + (size_t)min(bm + r1, M - 1) * K + c1;
    const half_t* gAhi0 = A + (size_t)min(bm + 128 + r0, M - 1) * K + c0;
    const half_t* gAhi1 = A + (size_t)min(bm + 128 + r1, M - 1) * K + c1;
    const half_t* gBlo0 = W + (size_t)(bn + r0) * K + c0;
    const half_t* gBlo1 = W + (size_t)(bn + r1) * K + c1;
    const half_t* gBhi0 = W + (size_t)(bn + 128 + r0) * K + c0;
    const half_t* gBhi1 = W + (size_t)(bn + 128 + r1) * K + c1;
    const int dst0 = w * 512;

#define STAGE_A(buf, kt) do {                                                  \
    GLD(gAlo0 + (size_t)(kt) * 64, &sm[buf][dst0]);                            \
    GLD(gAlo1 + (size_t)(kt) * 64, &sm[buf][4096 + dst0]);                     \
    GLD(gAhi0 + (size_t)(kt) * 64, &sm[buf][8192 + dst0]);                     \
    GLD(gAhi1 + (size_t)(kt) * 64, &sm[buf][12288 + dst0]);                    \
} while (0)
#define STAGE_B(buf, kt) do {                                                  \
    GLD(gBlo0 + (size_t)(kt) * 64, &sm[buf][16384 + dst0]);                    \
    GLD(gBlo1 + (size_t)(kt) * 64, &sm[buf][20480 + dst0]);                    \
    GLD(gBhi0 + (size_t)(kt) * 64, &sm[buf][24576 + dst0]);                    \
    GLD(gBhi1 + (size_t)(kt) * 64, &sm[buf][28672 + dst0]);                    \
} while (0)

    f32x4 acc[8][4] = {};

    // prologue: A0+B0 -> buf0 (8 GLD), B1 -> buf1 (4 GLD); vmcnt(4) lands A0,B0.
    STAGE_A(0, 0); STAGE_B(0, 0);
    STAGE_B(1, (NT > 1) ? 1 : 0);
    WAITV4();
    BAR();

#define TILE(cur, nxt, tt) do {                                                 \
    const char* smA = (const char*)&sm[cur][0];                                 \
    const char* smB = (const char*)&sm[cur][16384];                             \
    const int kA = ((tt) + 1 < NT) ? (tt) + 1 : NT - 1;                         \
    const int kB = ((tt) + 2 < NT) ? (tt) + 2 : NT - 1;                         \
    STAGE_A(nxt, kA);   /* earliest possible issue; nxt proven drained */       \
    f16x8 bf[4][2], af[8][2];                                                   \
    _Pragma("unroll")                                                           \
    for (int nj = 0; nj < 4; nj++) {                                            \
        bf[nj][0] = LDF(smB, wn + nj * 16 + fr, 0);                             \
        bf[nj][1] = LDF(smB, wn + nj * 16 + fr, 1);                             \
    }                                                                           \
    _Pragma("unroll")                                                           \
    for (int mi = 0; mi < 8; mi++) {                                            \
        af[mi][0] = LDF(smA, wm + mi * 16 + fr, 0);                             \
        af[mi][1] = LDF(smA, wm + mi * 16 + fr, 1);                             \
    }                                                                           \
    __builtin_amdgcn_s_setprio(1);                                              \
    _Pragma("unroll")                                                           \
    for (int mi = 0; mi < 4; mi++)                                              \
        _Pragma("unroll")                                                       \
        for (int nj = 0; nj < 4; nj++) {                                        \
            MM(mi, nj, af[mi][0], bf[nj][0]);                                   \
            MM(mi, nj, af[mi][1], bf[nj][1]);                                   \
        }                                                                       \
    __builtin_amdgcn_s_setprio(0);                                              \
    LGKM0();  /* this wave's 24 reads of cur drained */                         \
    BAR();    /* => block-wide: cur fully drained */                            \
    STAGE_B(cur, kB);                                                           \
    __builtin_amdgcn_s_setprio(1);                                              \
    _Pragma("unroll")                                                           \
    for (int mi = 4; mi < 8; mi++)                                              \
        _Pragma("unroll")                                                       \
        for (int nj = 0; nj < 4; nj++) {                                        \
            MM(mi, nj, af[mi][0], bf[nj][0]);                                   \
            MM(mi, nj, af[mi][1], bf[nj][1]);                                   \
        }                                                                       \
    __builtin_amdgcn_s_setprio(0);                                              \
    WAITV4(); /* drains B(t+1)+A(t+1); keeps B(t+2)'s 4 in flight */            \
    BAR();                                                                      \
} while (0)

    for (int tt = 0; tt < NT; tt += 2) {
        TILE(0, 1, tt);
        TILE(1, 0, tt + 1);
    }
    WAITV0();
#undef TILE
#undef STAGE_A
#undef STAGE_B

    // epilogue: D frag mapping col = lane&15, row = (lane>>4)*4 + r
    const int col0 = bn + wn + fr;
#pragma unroll
    for (int mi = 0; mi < 8; mi++) {
        int rb = bm + wm + mi * 16 + fq * 4;
#pragma unroll
        for (int nj = 0; nj < 4; nj++) {
            int col = col0 + nj * 16;
            float bv = bias[col];
#pragma unroll
            for (int r = 0; r < 4; r++) {
                int row = rb + r;
                if (row < M) {
                    float v = acc[mi][nj][r] + bv;
                    if (ACT == 1) v = fmaxf(v, 0.f);
                    if (ACT == 2) v = 0.5f * v * (1.f + erff(v * 0.70710678118f));
                    C[(size_t)row * N + col] = (OUT_T)v;
                }
            }
        }
    }
}

// ---------------- launch ----------------
extern "C" void kernel_launch(void* const* d_in, const int* in_sizes, int n_in,
                              void* d_out, int out_size, void* d_ws, size_t ws_size,
                              hipStream_t stream) {
    const float* x     = (const float*)d_in[0];
    const int*   eidx  = (const int*)d_in[1];
    const float* gn_w  = (const float*)d_in[2];
    const float* gn_b  = (const float*)d_in[3];
    const float* gn_ms = (const float*)d_in[4];
    const float* w1    = (const float*)d_in[5];
    const float* b1    = (const float*)d_in[6];
    const float* w2    = (const float*)d_in[7];
    const float* b2    = (const float*)d_in[8];
    const float* p1    = (const float*)d_in[9];
    const float* pb1   = (const float*)d_in[10];
    const float* p2    = (const float*)d_in[11];
    const float* pb2   = (const float*)d_in[12];

    const int Nn = in_sizes[0] / D_PROT;   // 50000
    const int E  = in_sizes[1] / 2;        // 400000
    const int M  = Nn;

    char* ws = (char*)d_ws;
    size_t off = 0;
    auto alloc = [&](size_t bytes) {
        void* p = ws + off;
        off += (bytes + 255) & ~(size_t)255;
        return p;
    };
    half_t* w1h    = (half_t*)alloc((size_t)D_PROT * D_PROT * 2);
    half_t* w2h    = (half_t*)alloc((size_t)D_PROT * D_PROT * 2);
    half_t* p1h    = (half_t*)alloc((size_t)D_TEXT * D_PROT * 2);
    half_t* p2h    = (half_t*)alloc((size_t)D_TEXT * D_TEXT * 2);
    int*    deg    = (int*)alloc((size_t)Nn * 4);
    float*  dinv   = (float*)alloc((size_t)Nn * 4);
    int*    rowptr = (int*)alloc((size_t)(Nn + 1) * 4);
    int*    fillc  = (int*)alloc((size_t)Nn * 4);
    int*    bsum   = (int*)alloc(1024);
    int*    boff   = (int*)alloc(1024);
    int*    colidx = (int*)alloc((size_t)E * 4);
    float*  sums   = (float*)alloc(D_PROT * 4);
    float*  sumsq  = (float*)alloc(D_PROT * 4);
    float*  gnab   = (float*)alloc(2 * D_PROT * 4);
    half_t* buf1   = (half_t*)alloc((size_t)Nn * D_PROT * 2);
    half_t* buf2   = (half_t*)alloc((size_t)Nn * D_PROT * 2);
    half_t* big    = (half_t*)alloc((size_t)Nn * D_TEXT * 2);

    const int* esrc = eidx;
    const int* edst = eidx + E;

    hipMemsetAsync(deg, 0, (size_t)Nn * 4, stream);
    hipMemsetAsync(fillc, 0, (size_t)Nn * 4, stream);
    hipMemsetAsync(rowptr, 0, (size_t)(Nn + 1) * 4, stream);
    hipMemsetAsync(sums, 0, D_PROT * 4, stream);
    hipMemsetAsync(sumsq, 0, D_PROT * 4, stream);

    k_cvt4<<<(D_PROT * D_PROT / 4 + 255) / 256, 256, 0, stream>>>(w1, w1h, D_PROT * D_PROT / 4);
    k_cvt4<<<(D_PROT * D_PROT / 4 + 255) / 256, 256, 0, stream>>>(w2, w2h, D_PROT * D_PROT / 4);
    k_cvt4<<<(D_TEXT * D_PROT / 4 + 255) / 256, 256, 0, stream>>>(p1, p1h, D_TEXT * D_PROT / 4);
    k_cvt4<<<(D_TEXT * D_TEXT / 4 + 255) / 256, 256, 0, stream>>>(p2, p2h, D_TEXT * D_TEXT / 4);

    int eb = (E + 255) / 256;
    int nb = (Nn + 255) / 256;
    k_deg<<<eb, 256, 0, stream>>>(edst, E, deg);
    k_dinv<<<nb, 256, 0, stream>>>(deg, dinv, Nn);
    k_blocksum<<<nb, 256, 0, stream>>>(deg, bsum, Nn);
    k_scan_bsum<<<1, 1, 0, stream>>>(bsum, boff, nb);
    k_scan_final<<<nb, 256, 0, stream>>>(deg, boff, rowptr, Nn);
    k_fill<<<eb, 256, 0, stream>>>(esrc, edst, E, rowptr, fillc, colidx);

    k_gnreduce<<<256, 256, 0, stream>>>(x, sums, sumsq, Nn);
    k_gnfinal<<<2, 256, 0, stream>>>(sums, sumsq, gn_w, gn_b, gn_ms, gnab, 1.0f / (float)Nn);
    int n4 = Nn * D_PROT / 4;
    k_gnnorm<<<(n4 + 255) / 256, 256, 0, stream>>>(x, gnab, buf1, n4);

    const int mt256 = (M + 255) / 256;

    // conv1: agg -> gemm+relu
    k_agg<<<Nn, 128, 0, stream>>>(buf1, buf2, rowptr, colidx, dinv);
    {
        dim3 g(D_PROT / 256, mt256);
        k_gemm8<1, half_t><<<g, 512, 0, stream>>>(buf2, w1h, b1, buf1, M, D_PROT, D_PROT);
    }
    // conv2
    k_agg<<<Nn, 128, 0, stream>>>(buf1, buf2, rowptr, colidx, dinv);
    {
        dim3 g(D_PROT / 256, mt256);
        k_gemm8<1, half_t><<<g, 512, 0, stream>>>(buf2, w2h, b2, buf1, M, D_PROT, D_PROT);
    }
    // proj1 + gelu
    {
        dim3 g(D_TEXT / 256, mt256);
        k_gemm8<2, half_t><<<g, 512, 0, stream>>>(buf1, p1h, pb1, big, M, D_TEXT, D_PROT);
    }
    // proj2 -> fp32 out
    {
        dim3 g(D_TEXT / 256, mt256);
        k_gemm8<0, float><<<g, 512, 0, stream>>>(big, p2h, pb2, (float*)d_out, M, D_TEXT, D_TEXT);
    }
}

// Round 8
// 1300.495 us; speedup vs baseline: 1.5494x; 1.5494x over previous
//
#include <hip/hip_runtime.h>
#include <math.h>

typedef _Float16 half_t;
typedef _Float16 f16x2 __attribute__((ext_vector_type(2)));
typedef _Float16 f16x4 __attribute__((ext_vector_type(4)));
typedef _Float16 f16x8 __attribute__((ext_vector_type(8)));
typedef float f32x4 __attribute__((ext_vector_type(4)));

#define D_PROT 512
#define D_TEXT 2048

// ---------------- utility: fp32 -> fp16 convert (vector x4) ----------------
__global__ void k_cvt4(const float* __restrict__ s, half_t* __restrict__ d, int n4) {
    int i = blockIdx.x * 256 + threadIdx.x;
    if (i < n4) {
        float4 v = ((const float4*)s)[i];
        f16x4 o;
        o.x = (_Float16)v.x; o.y = (_Float16)v.y;
        o.z = (_Float16)v.z; o.w = (_Float16)v.w;
        ((f16x4*)d)[i] = o;
    }
}

// ---------------- degree histogram ----------------
__global__ void k_deg(const int* __restrict__ dst, int E, int* __restrict__ deg) {
    int i = blockIdx.x * 256 + threadIdx.x;
    if (i < E) atomicAdd(&deg[dst[i]], 1);
}

__global__ void k_dinv(const int* __restrict__ deg, float* __restrict__ dinv, int n) {
    int i = blockIdx.x * 256 + threadIdx.x;
    if (i < n) dinv[i] = rsqrtf((float)deg[i] + 1.0f);
}

// ---------------- prefix sum (3-kernel) ----------------
__global__ void k_blocksum(const int* __restrict__ deg, int* __restrict__ bsum, int n) {
    __shared__ int sd[256];
    int i = blockIdx.x * 256 + threadIdx.x;
    sd[threadIdx.x] = (i < n) ? deg[i] : 0;
    __syncthreads();
    for (int s = 128; s > 0; s >>= 1) {
        if (threadIdx.x < s) sd[threadIdx.x] += sd[threadIdx.x + s];
        __syncthreads();
    }
    if (threadIdx.x == 0) bsum[blockIdx.x] = sd[0];
}

__global__ void k_scan_bsum(const int* __restrict__ bsum, int* __restrict__ boff, int nb) {
    if (threadIdx.x == 0 && blockIdx.x == 0) {
        int acc = 0;
        for (int i = 0; i < nb; i++) { boff[i] = acc; acc += bsum[i]; }
    }
}

__global__ void k_scan_final(const int* __restrict__ deg, const int* __restrict__ boff,
                             int* __restrict__ rowptr, int n) {
    __shared__ int sd[256];
    int i = blockIdx.x * 256 + threadIdx.x;
    int v = (i < n) ? deg[i] : 0;
    sd[threadIdx.x] = v;
    __syncthreads();
    for (int s = 1; s < 256; s <<= 1) {
        int t2 = (threadIdx.x >= s) ? sd[threadIdx.x - s] : 0;
        __syncthreads();
        sd[threadIdx.x] += t2;
        __syncthreads();
    }
    if (i < n) rowptr[i + 1] = boff[blockIdx.x] + sd[threadIdx.x];
}

// ---------------- CSR fill (atomic append) ----------------
__global__ void k_fill(const int* __restrict__ src, const int* __restrict__ dst, int E,
                       const int* __restrict__ rowptr, int* __restrict__ fill,
                       int* __restrict__ colidx) {
    int i = blockIdx.x * 256 + threadIdx.x;
    if (i < E) {
        int d = dst[i];
        int pos = atomicAdd(&fill[d], 1);
        colidx[rowptr[d] + pos] = src[i];
    }
}

// ---------------- GraphNorm ----------------
__global__ void k_gnreduce(const float* __restrict__ x, float* __restrict__ sums,
                           float* __restrict__ sumsq, int Nn) {
    int t = threadIdx.x;
    int c = t * 2;
    float s0 = 0, s1 = 0, q0 = 0, q1 = 0;
    for (int r = blockIdx.x; r < Nn; r += gridDim.x) {
        float2 v = *(const float2*)(x + (size_t)r * D_PROT + c);
        s0 += v.x; s1 += v.y; q0 += v.x * v.x; q1 += v.y * v.y;
    }
    atomicAdd(&sums[c], s0);  atomicAdd(&sums[c + 1], s1);
    atomicAdd(&sumsq[c], q0); atomicAdd(&sumsq[c + 1], q1);
}

__global__ void k_gnfinal(const float* __restrict__ sums, const float* __restrict__ sumsq,
                          const float* __restrict__ w, const float* __restrict__ b,
                          const float* __restrict__ ms, float* __restrict__ ab, float invN) {
    int d = blockIdx.x * 256 + threadIdx.x;
    if (d < D_PROT) {
        float mean = sums[d] * invN;
        float m2 = sumsq[d] * invN;
        float mm = mean * ms[d];
        float var = m2 - 2.f * mm * mean + mm * mm;
        float rstd = rsqrtf(var + 1e-5f);
        float a = rstd * w[d];
        ab[d] = a;
        ab[D_PROT + d] = b[d] - mm * a;
    }
}

__global__ void k_gnnorm(const float* __restrict__ x, const float* __restrict__ ab,
                         half_t* __restrict__ h, int n4) {
    int i = blockIdx.x * 256 + threadIdx.x;
    if (i < n4) {
        size_t idx = (size_t)i * 4;
        float4 v = *(const float4*)(x + idx);
        int d = (int)(idx & (D_PROT - 1));
        const float* a = ab;
        const float* bb = ab + D_PROT;
        f16x4 o;
        o.x = (_Float16)(v.x * a[d]     + bb[d]);
        o.y = (_Float16)(v.y * a[d + 1] + bb[d + 1]);
        o.z = (_Float16)(v.z * a[d + 2] + bb[d + 2]);
        o.w = (_Float16)(v.w * a[d + 3] + bb[d + 3]);
        *(f16x4*)(h + idx) = o;
    }
}

// ---------------- SGConv aggregation (CSR gather, 4-way unrolled) ----------------
__global__ void k_agg(const half_t* __restrict__ h, half_t* __restrict__ out,
                      const int* __restrict__ rowptr, const int* __restrict__ colidx,
                      const float* __restrict__ dinv) {
    int node = blockIdx.x;
    int t = threadIdx.x;
    float di = dinv[node];
    int beg = rowptr[node], end = rowptr[node + 1];
    const f16x4* hp = (const f16x4*)h;
    f16x4 sv = hp[node * 128 + t];
    float dii = di * di;
    float a0 = (float)sv.x * dii, a1 = (float)sv.y * dii;
    float a2 = (float)sv.z * dii, a3 = (float)sv.w * dii;
    int e = beg;
    for (; e + 4 <= end; e += 4) {
        int s0 = colidx[e],     s1 = colidx[e + 1];
        int s2 = colidx[e + 2], s3 = colidx[e + 3];
        float w0 = dinv[s0] * di, w1 = dinv[s1] * di;
        float w2 = dinv[s2] * di, w3 = dinv[s3] * di;
        f16x4 v0 = hp[s0 * 128 + t], v1 = hp[s1 * 128 + t];
        f16x4 v2 = hp[s2 * 128 + t], v3 = hp[s3 * 128 + t];
        a0 += w0 * (float)v0.x + w1 * (float)v1.x + w2 * (float)v2.x + w3 * (float)v3.x;
        a1 += w0 * (float)v0.y + w1 * (float)v1.y + w2 * (float)v2.y + w3 * (float)v3.y;
        a2 += w0 * (float)v0.z + w1 * (float)v1.z + w2 * (float)v2.z + w3 * (float)v3.z;
        a3 += w0 * (float)v0.w + w1 * (float)v1.w + w2 * (float)v2.w + w3 * (float)v3.w;
    }
    for (; e < end; ++e) {
        int s = colidx[e];
        float wgt = dinv[s] * di;
        f16x4 v = hp[s * 128 + t];
        a0 += wgt * (float)v.x; a1 += wgt * (float)v.y;
        a2 += wgt * (float)v.z; a3 += wgt * (float)v.w;
    }
    f16x4 o;
    o.x = (_Float16)a0; o.y = (_Float16)a1; o.z = (_Float16)a2; o.w = (_Float16)a3;
    ((f16x4*)out)[node * 128 + t] = o;
}

// ---------------- 256^2 8-wave GEMM, 4-buffer BK=32 rotation, 1 barrier/tile ---------
// C[M,N] = A[M,K] @ W[N,K]^T + bias, activation. N % 256 == 0, K % 128 == 0 (NT%4==0).
// LDS: 4 bufs x 32KB (A rows 0..255 x 32 halves at [0,8192) halves, B at [8192,16384)).
// Swizzle (BK=32, 64B rows): read byte ^= (((row>>1)&3)<<4) -> 8 slots x 2 lanes = free;
// staging source pre-swizzled with involution q ^= (((q>>6)&3)<<3) (bits[7:6] untouched).
// Pipeline: tile t reads buf[t&3]; stages tile t+3 into buf[(t+3)&3] (last read during
// tile t-1; those reads are consumed before t-1's end barrier -> WAR safe with the ONE
// end-of-tile barrier). vmcnt ledger: +4 GLD per tile, WAITV8 at end drains t+1's 4,
// keeps {t+2,t+3}'s 8 in flight. Never vmcnt(0) in loop. No mid-tile barriers at all:
// ds_reads and MFMAs flow freely; compiler pipelines; per-wave lgkm ordering suffices.
// Register budget: acc 128 + 4 B-frags + ~2 A-frags live ~ 190 VGPR (R7's 24-frag
// version spilled: WRITE_SIZE +150MB scratch — avoid holding all frags live).
#define FENCE() asm volatile("" ::: "memory")
#define BAR()   do { FENCE(); __builtin_amdgcn_s_barrier(); FENCE(); } while (0)
#define WAITV8() asm volatile("s_waitcnt vmcnt(8)" ::: "memory")
#define WAITV0() asm volatile("s_waitcnt vmcnt(0)" ::: "memory")
#define GLD(src, dst) __builtin_amdgcn_global_load_lds( \
    (const __attribute__((address_space(1))) void*)(src), \
    (__attribute__((address_space(3))) void*)(dst), 16, 0, 0)
// frag read: byte = row*64 + fq*16, swizzled by row bits [2:1]
#define LDF(base, row) \
    (*(const f16x8*)((base) + ((((row) * 64 + fqo)) ^ ((((row) >> 1) & 3) << 4))))
#define MM(mi, nj, A_, B_) \
    acc[mi][nj] = __builtin_amdgcn_mfma_f32_16x16x32_f16(A_, B_, acc[mi][nj], 0, 0, 0)

template <int ACT, typename OUT_T>
__global__ __launch_bounds__(512, 2) void k_gemm8(const half_t* __restrict__ A,
                                                  const half_t* __restrict__ W,
                                                  const float* __restrict__ bias,
                                                  OUT_T* __restrict__ C,
                                                  int M, int N, int K) {
    __shared__ half_t sm[4][16384];
    // XCD-chunked bijective remap (nwg % 8 == 0 in all our launches): A fetched ~once.
    const int gx = gridDim.x;
    const int nwg = gx * gridDim.y;
    int b = blockIdx.y * gx + blockIdx.x;
    int w8 = ((nwg & 7) == 0) ? (b & 7) * (nwg >> 3) + (b >> 3) : b;
    const int bn = (w8 % gx) * 256;
    const int bm = (w8 / gx) * 256;

    const int t = threadIdx.x;
    const int w = t >> 6, lane = t & 63;
    const int fr = lane & 15, fq = lane >> 4;
    const int fqo = fq * 16;
    const int wm = (w >> 2) * 128, wn = (w & 3) * 64;
    const int NT = K >> 5;   // BK=32 tiles; NT % 4 == 0 for K in {512, 2048}

    // staging: 4 units of 4096 halves {Alo rows0-127, Ahi rows128-255, Blo, Bhi}.
    // Per-thread source index q in [0,4096) pre-swizzled: s = q ^ (((q>>6)&3)<<3).
    int q = w * 512 + lane * 8;
    int s = q ^ (((q >> 6) & 3) << 3);
    int r = s >> 5, c = s & 31;
    const half_t* gAlo = A + (size_t)min(bm + r, M - 1) * K + c;
    const half_t* gAhi = A + (size_t)min(bm + 128 + r, M - 1) * K + c;
    const half_t* gBlo = W + (size_t)(bn + r) * K + c;
    const half_t* gBhi = W + (size_t)(bn + 128 + r) * K + c;
    const int dst0 = w * 512;   // wave-uniform LDS base (lane*16B added by HW)

#define STAGE(buf, kt) do {                                                    \
    GLD(gAlo + (size_t)(kt) * 32, &sm[buf][dst0]);                             \
    GLD(gAhi + (size_t)(kt) * 32, &sm[buf][4096 + dst0]);                      \
    GLD(gBlo + (size_t)(kt) * 32, &sm[buf][8192 + dst0]);                      \
    GLD(gBhi + (size_t)(kt) * 32, &sm[buf][12288 + dst0]);                     \
} while (0)

    f32x4 acc[8][4] = {};

    // prologue: tiles 0,1,2 -> bufs 0,1,2. WAITV8 lands tile0, keeps {t1,t2}.
    STAGE(0, 0);
    STAGE(1, 1);
    STAGE(2, 2);
    WAITV8();
    BAR();

#define TILE(cur, tt) do {                                                     \
    const char* smA = (const char*)&sm[cur][0];                                \
    const char* smB = smA + 16384;                                             \
    const int kt = ((tt) + 3 < NT) ? (tt) + 3 : NT - 1;                        \
    STAGE(((cur) + 3) & 3, kt);                                                \
    f16x8 b0 = LDF(smB, wn + fr);                                              \
    f16x8 b1 = LDF(smB, wn + 16 + fr);                                         \
    f16x8 b2 = LDF(smB, wn + 32 + fr);                                         \
    f16x8 b3 = LDF(smB, wn + 48 + fr);                                         \
    __builtin_amdgcn_s_setprio(1);                                             \
    _Pragma("unroll")                                                          \
    for (int mi = 0; mi < 8; mi++) {                                           \
        f16x8 a = LDF(smA, wm + mi * 16 + fr);                                 \
        MM(mi, 0, a, b0); MM(mi, 1, a, b1);                                    \
        MM(mi, 2, a, b2); MM(mi, 3, a, b3);                                    \
    }                                                                          \
    __builtin_amdgcn_s_setprio(0);                                             \
    WAITV8();  /* drains tile tt+1's 4 loads; keeps {tt+2, tt+3} in flight */  \
    BAR();                                                                     \
} while (0)

    for (int tt = 0; tt < NT; tt += 4) {
        TILE(0, tt);
        TILE(1, tt + 1);
        TILE(2, tt + 2);
        TILE(3, tt + 3);
    }
    WAITV0();
#undef TILE
#undef STAGE

    // epilogue: D frag mapping col = lane&15, row = (lane>>4)*4 + r
    const int col0 = bn + wn + fr;
#pragma unroll
    for (int mi = 0; mi < 8; mi++) {
        int rb = bm + wm + mi * 16 + fq * 4;
#pragma unroll
        for (int nj = 0; nj < 4; nj++) {
            int col = col0 + nj * 16;
            float bv = bias[col];
#pragma unroll
            for (int rr = 0; rr < 4; rr++) {
                int row = rb + rr;
                if (row < M) {
                    float v = acc[mi][nj][rr] + bv;
                    if (ACT == 1) v = fmaxf(v, 0.f);
                    if (ACT == 2) v = 0.5f * v * (1.f + erff(v * 0.70710678118f));
                    C[(size_t)row * N + col] = (OUT_T)v;
                }
            }
        }
    }
}

// ---------------- launch ----------------
extern "C" void kernel_launch(void* const* d_in, const int* in_sizes, int n_in,
                              void* d_out, int out_size, void* d_ws, size_t ws_size,
                              hipStream_t stream) {
    const float* x     = (const float*)d_in[0];
    const int*   eidx  = (const int*)d_in[1];
    const float* gn_w  = (const float*)d_in[2];
    const float* gn_b  = (const float*)d_in[3];
    const float* gn_ms = (const float*)d_in[4];
    const float* w1    = (const float*)d_in[5];
    const float* b1    = (const float*)d_in[6];
    const float* w2    = (const float*)d_in[7];
    const float* b2    = (const float*)d_in[8];
    const float* p1    = (const float*)d_in[9];
    const float* pb1   = (const float*)d_in[10];
    const float* p2    = (const float*)d_in[11];
    const float* pb2   = (const float*)d_in[12];

    const int Nn = in_sizes[0] / D_PROT;   // 50000
    const int E  = in_sizes[1] / 2;        // 400000
    const int M  = Nn;

    char* ws = (char*)d_ws;
    size_t off = 0;
    auto alloc = [&](size_t bytes) {
        void* p = ws + off;
        off += (bytes + 255) & ~(size_t)255;
        return p;
    };
    half_t* w1h    = (half_t*)alloc((size_t)D_PROT * D_PROT * 2);
    half_t* w2h    = (half_t*)alloc((size_t)D_PROT * D_PROT * 2);
    half_t* p1h    = (half_t*)alloc((size_t)D_TEXT * D_PROT * 2);
    half_t* p2h    = (half_t*)alloc((size_t)D_TEXT * D_TEXT * 2);
    int*    deg    = (int*)alloc((size_t)Nn * 4);
    float*  dinv   = (float*)alloc((size_t)Nn * 4);
    int*    rowptr = (int*)alloc((size_t)(Nn + 1) * 4);
    int*    fillc  = (int*)alloc((size_t)Nn * 4);
    int*    bsum   = (int*)alloc(1024);
    int*    boff   = (int*)alloc(1024);
    int*    colidx = (int*)alloc((size_t)E * 4);
    float*  sums   = (float*)alloc(D_PROT * 4);
    float*  sumsq  = (float*)alloc(D_PROT * 4);
    float*  gnab   = (float*)alloc(2 * D_PROT * 4);
    half_t* buf1   = (half_t*)alloc((size_t)Nn * D_PROT * 2);
    half_t* buf2   = (half_t*)alloc((size_t)Nn * D_PROT * 2);
    half_t* big    = (half_t*)alloc((size_t)Nn * D_TEXT * 2);

    const int* esrc = eidx;
    const int* edst = eidx + E;

    hipMemsetAsync(deg, 0, (size_t)Nn * 4, stream);
    hipMemsetAsync(fillc, 0, (size_t)Nn * 4, stream);
    hipMemsetAsync(rowptr, 0, (size_t)(Nn + 1) * 4, stream);
    hipMemsetAsync(sums, 0, D_PROT * 4, stream);
    hipMemsetAsync(sumsq, 0, D_PROT * 4, stream);

    k_cvt4<<<(D_PROT * D_PROT / 4 + 255) / 256, 256, 0, stream>>>(w1, w1h, D_PROT * D_PROT / 4);
    k_cvt4<<<(D_PROT * D_PROT / 4 + 255) / 256, 256, 0, stream>>>(w2, w2h, D_PROT * D_PROT / 4);
    k_cvt4<<<(D_TEXT * D_PROT / 4 + 255) / 256, 256, 0, stream>>>(p1, p1h, D_TEXT * D_PROT / 4);
    k_cvt4<<<(D_TEXT * D_TEXT / 4 + 255) / 256, 256, 0, stream>>>(p2, p2h, D_TEXT * D_TEXT / 4);

    int eb = (E + 255) / 256;
    int nb = (Nn + 255) / 256;
    k_deg<<<eb, 256, 0, stream>>>(edst, E, deg);
    k_dinv<<<nb, 256, 0, stream>>>(deg, dinv, Nn);
    k_blocksum<<<nb, 256, 0, stream>>>(deg, bsum, Nn);
    k_scan_bsum<<<1, 1, 0, stream>>>(bsum, boff, nb);
    k_scan_final<<<nb, 256, 0, stream>>>(deg, boff, rowptr, Nn);
    k_fill<<<eb, 256, 0, stream>>>(esrc, edst, E, rowptr, fillc, colidx);

    k_gnreduce<<<256, 256, 0, stream>>>(x, sums, sumsq, Nn);
    k_gnfinal<<<2, 256, 0, stream>>>(sums, sumsq, gn_w, gn_b, gn_ms, gnab, 1.0f / (float)Nn);
    int n4 = Nn * D_PROT / 4;
    k_gnnorm<<<(n4 + 255) / 256, 256, 0, stream>>>(x, gnab, buf1, n4);

    const int mt256 = (M + 255) / 256;

    // conv1: agg -> gemm+relu
    k_agg<<<Nn, 128, 0, stream>>>(buf1, buf2, rowptr, colidx, dinv);
    {
        dim3 g(D_PROT / 256, mt256);
        k_gemm8<1, half_t><<<g, 512, 0, stream>>>(buf2, w1h, b1, buf1, M, D_PROT, D_PROT);
    }
    // conv2
    k_agg<<<Nn, 128, 0, stream>>>(buf1, buf2, rowptr, colidx, dinv);
    {
        dim3 g(D_PROT / 256, mt256);
        k_gemm8<1, half_t><<<g, 512, 0, stream>>>(buf2, w2h, b2, buf1, M, D_PROT, D_PROT);
    }
    // proj1 + gelu
    {
        dim3 g(D_TEXT / 256, mt256);
        k_gemm8<2, half_t><<<g, 512, 0, stream>>>(buf1, p1h, pb1, big, M, D_TEXT, D_PROT);
    }
    // proj2 -> fp32 out
    {
        dim3 g(D_TEXT / 256, mt256);
        k_gemm8<0, float><<<g, 512, 0, stream>>>(big, p2h, pb2, (float*)d_out, M, D_TEXT, D_TEXT);
    }
}